// Round 18
// baseline (357.516 us; speedup 1.0000x reference)
//
#include <hip/hip_runtime.h>
#include <hip/hip_bf16.h>
#include <stdint.h>

#define NC 2112   // H*DK*2 + DK = 16*64*2 + 64

typedef __attribute__((ext_vector_type(8))) short bf16x8;
typedef __attribute__((ext_vector_type(4))) float f32x4;

static __device__ __forceinline__ unsigned short f2bf(float f) {
  uint32_t u = __builtin_bit_cast(uint32_t, f);
  u += 0x7FFFu + ((u >> 16) & 1u);
  return (unsigned short)(u >> 16);
}
// native path: compiler emits v_cvt_pk_bf16_f32 (RNE, same bits as f2bf)
static __device__ __forceinline__ unsigned short f2bf_n(float f) {
  __hip_bfloat16 h = __float2bfloat16(f);
  return __builtin_bit_cast(unsigned short, h);
}
static __device__ __forceinline__ float bf2f(unsigned short u) {
  return __builtin_bit_cast(float, ((uint32_t)u) << 16);
}
static __device__ __forceinline__ float exp2_fast(float x) {
  return __builtin_amdgcn_exp2f(x);   // single v_exp_f32 (2^x on gfx950)
}
static __device__ __forceinline__ void gload16(const unsigned short* g, unsigned short* l) {
  __builtin_amdgcn_global_load_lds((const __attribute__((address_space(1))) void*)g,
                                   (__attribute__((address_space(3))) void*)l, 16, 0, 0);
}

// ---------------- 1. q fp32 -> bf16 ----------------
__global__ void k_convert_q(const float* __restrict__ q, unsigned short* __restrict__ qbf) {
  int i = blockIdx.x * blockDim.x + threadIdx.x;   // one float4 each; 2,097,152 total
  float4 v = ((const float4*)q)[i];
  ushort4 o;
  o.x = f2bf(v.x); o.y = f2bf(v.y); o.z = f2bf(v.z); o.w = f2bf(v.w);
  ((ushort4*)qbf)[i] = o;
}

// ---------------- 2. build WcatT[2112][1024] bf16 (N-major, k contiguous) ----------------
// Wq columns pre-scaled by 0.125*log2(e) so attn can use exp2 directly.
__global__ void k_build_wcatT(const float* __restrict__ Wq, const float* __restrict__ Wk,
                              const float* __restrict__ Wv, unsigned short* __restrict__ wt) {
  int t = blockIdx.x * blockDim.x + threadIdx.x;   // c*128 + k/8 ; 270,336 total
  int c = t >> 7;
  int k0 = (t & 127) << 3;
  const float qs = 0.18033688011116027f;  // 0.125 * log2(e)
  unsigned short o[8];
#pragma unroll
  for (int i = 0; i < 8; ++i) {
    int k = k0 + i;
    float v;
    if (c < 1024)      v = Wq[((size_t)(c >> 6) * 1024 + k) * 64 + (c & 63)] * qs;
    else if (c < 2048) v = Wk[((size_t)((c - 1024) >> 6) * 1024 + k) * 64 + (c & 63)];
    else               v = Wv[(size_t)k * 64 + (c - 2048)];
    o[i] = f2bf(v);
  }
  *(ushort4*)&wt[(size_t)c * 1024 + k0]     = *(ushort4*)&o[0];
  *(ushort4*)&wt[(size_t)c * 1024 + k0 + 4] = *(ushort4*)&o[4];
}

// ---------------- 3. GEMM (m97 pattern); epilogue splits Q->Gq, K->kst panels, V->vst ----------------
__global__ __launch_bounds__(256) void k_gemm(const unsigned short* __restrict__ A,
                                              const unsigned short* __restrict__ Bt,
                                              unsigned short* __restrict__ Gq,
                                              unsigned short* __restrict__ kst,
                                              unsigned short* __restrict__ vst) {
  __shared__ unsigned short As[128 * 32];   // linear: required by global_load_lds
  __shared__ unsigned short Bs[128 * 32];
  const int L = blockIdx.x;                 // 1088 = 8 XCD * 136
  const int xcd = L & 7, l = L >> 3;
  const int tn = l >> 3;
  const int tm = xcd * 8 + (l & 7);
  const int rowBase = tm * 128, colBase = tn * 128;
  const int t = threadIdx.x;
  const int wave = t >> 6, lane = t & 63;
  const int wm = wave >> 1, wn = wave & 1;
  const int l15 = lane & 15, l4 = lane >> 4;
  f32x4 acc[4][4] = {};
  for (int kt = 0; kt < 1024; kt += 32) {
#pragma unroll
    for (int i = 0; i < 2; ++i) {
      int e = (t + i * 256) * 8;          // elem index in 128x32 tile
      int r = e >> 5, c = e & 31;
      gload16(&A[(size_t)(rowBase + r) * 1024 + kt + c], &As[e]);
      int rb = colBase + r; rb = rb < NC ? rb : (NC - 1);   // clamp (dup row, never stored)
      gload16(&Bt[(size_t)rb * 1024 + kt + c], &Bs[e]);
    }
    __syncthreads();
    bf16x8 af[4], bfr[4];
#pragma unroll
    for (int m = 0; m < 4; ++m) af[m] = *(const bf16x8*)&As[(wm * 64 + m * 16 + l15) * 32 + l4 * 8];
#pragma unroll
    for (int n = 0; n < 4; ++n) bfr[n] = *(const bf16x8*)&Bs[(wn * 64 + n * 16 + l15) * 32 + l4 * 8];
#pragma unroll
    for (int m = 0; m < 4; ++m)
#pragma unroll
      for (int n = 0; n < 4; ++n)
        acc[m][n] = __builtin_amdgcn_mfma_f32_16x16x32_bf16(af[m], bfr[n], acc[m][n], 0, 0, 0);
    __syncthreads();
  }
#pragma unroll
  for (int m = 0; m < 4; ++m)
#pragma unroll
    for (int n = 0; n < 4; ++n) {
      int col = colBase + wn * 64 + n * 16 + l15;
      int row0 = rowBase + wm * 64 + m * 16 + l4 * 4;
      if (col < 1024) {
        // Q projections
#pragma unroll
        for (int i = 0; i < 4; ++i)
          Gq[(size_t)(row0 + i) * 1024 + col] = f2bf_n(acc[m][n][i]);
      } else if (col < 2048) {
        // K projections -> dense per-(b,h) panel
        int hh = (col - 1024) >> 6, dk = (col - 1024) & 63;
#pragma unroll
        for (int i = 0; i < 4; ++i) {
          int rg = row0 + i;
          kst[(((size_t)(rg >> 10) * 16 + hh) * 1024 + (rg & 1023)) * 64 + dk] = f2bf_n(acc[m][n][i]);
        }
      } else if (col < NC) {
        // V columns: write transposed into vst[b][d][j]
        int d = col - 2048;
#pragma unroll
        for (int i = 0; i < 4; ++i) {
          int rg = row0 + i;
          vst[((size_t)(rg >> 10) * 64 + d) * 1024 + (rg & 1023)] = f2bf_n(acc[m][n][i]);
        }
      }
    }
}

// ---------------- 4. attention: champion + register-stashed e across the barrier ----------------
// 8 waves x 512 threads, QBLK=32, single barrier, attn NT-stores BEFORE PV.
// Phase 1 keeps the 16 packed-bf16 e-groups in registers (32 VGPR); the store phase
// reads only 4 LDS values (row sums) and stores straight from registers.
__global__ __launch_bounds__(512, 4) void k_attn(const unsigned short* __restrict__ Gq,
                                                 const unsigned short* __restrict__ kst,
                                                 const unsigned short* __restrict__ vst,
                                                 float* __restrict__ attn,
                                                 float* __restrict__ head) {
  __shared__ unsigned short SP[32][1032];  // unnormalized exp(scores), bf16 (for PV)
  __shared__ float rs[32][8];              // per-row partial sums, per wave
  const int L = blockIdx.x;                // XCD swizzle: 4096 = 8 * 512
  const int wi = (L & 7) * 512 + (L >> 3);
  const int qt = wi & 31, b = (wi >> 5) & 7, h = wi >> 8;
  const int t = threadIdx.x, wave = t >> 6, lane = t & 63;
  const int l15 = lane & 15, l4 = lane >> 4;

  const unsigned short* Gqb = Gq + (size_t)b * 1024 * 1024;
  const unsigned short* Kb  = kst + (size_t)(b * 16 + h) * 1024 * 64;

  // Q fragments (B-operand): qf[m] covers q-rows qt*32 + m*16 + l15
  bf16x8 qf[2][2];
#pragma unroll
  for (int m = 0; m < 2; ++m)
#pragma unroll
    for (int ks = 0; ks < 2; ++ks)
      qf[m][ks] = *(const bf16x8*)&Gqb[(size_t)(qt * 32 + m * 16 + l15) * 1024 + h * 64 + ks * 32 + l4 * 8];

  // ---- phase 1: QK^T swapped (wave owns keys [wave*128,+128)) ----
  float psum[2] = {};    // row m*16+l15, this lane's share of 128 keys
  uint2 est[2][8];       // packed bf16 e-pairs, kept across the barrier (32 VGPR)
#pragma unroll
  for (int half = 0; half < 2; ++half) {
    bf16x8 kf[4][2];
#pragma unroll
    for (int kt = 0; kt < 4; ++kt) {
      int k0 = wave * 128 + half * 64 + kt * 16;
#pragma unroll
      for (int ks = 0; ks < 2; ++ks)
        kf[kt][ks] = *(const bf16x8*)&Kb[(size_t)(k0 + l15) * 64 + ks * 32 + l4 * 8];
    }
#pragma unroll
    for (int kt = 0; kt < 4; ++kt) {
      int k0 = wave * 128 + half * 64 + kt * 16;
#pragma unroll
      for (int m = 0; m < 2; ++m) {
        f32x4 s = {};
        __builtin_amdgcn_s_setprio(1);
        s = __builtin_amdgcn_mfma_f32_16x16x32_bf16(kf[kt][0], qf[m][0], s, 0, 0, 0);
        s = __builtin_amdgcn_mfma_f32_16x16x32_bf16(kf[kt][1], qf[m][1], s, 0, 0, 0);
        __builtin_amdgcn_s_setprio(0);
        // lane: q-row = m*16+l15 ; keys = k0 + l4*4 + i
        float e0 = exp2_fast(s[0]), e1 = exp2_fast(s[1]);
        float e2 = exp2_fast(s[2]), e3 = exp2_fast(s[3]);
        psum[m] += (e0 + e1) + (e2 + e3);
        uint32_t lo = (uint32_t)f2bf_n(e0) | ((uint32_t)f2bf_n(e1) << 16);
        uint32_t hi = (uint32_t)f2bf_n(e2) | ((uint32_t)f2bf_n(e3) << 16);
        uint2 u = {lo, hi};
        est[m][half * 4 + kt] = u;
        *(uint2*)&SP[m * 16 + l15][k0 + l4 * 4] = u;
      }
    }
  }
  // reduce over l4 lane bits (lanes 16,32 apart share the same q-row)
  psum[0] += __shfl_xor(psum[0], 16);
  psum[0] += __shfl_xor(psum[0], 32);
  psum[1] += __shfl_xor(psum[1], 16);
  psum[1] += __shfl_xor(psum[1], 32);
  if (l4 == 0) {
    rs[l15][wave]      = psum[0];
    rs[16 + l15][wave] = psum[1];
  }
  __syncthreads();

  // ---- attn write straight from registers (rows m*16+l15, this wave's 128 keys) ----
  size_t attn_base = ((size_t)(h * 8 + b) * 1024 + (size_t)qt * 32) * 1024;
#pragma unroll
  for (int m = 0; m < 2; ++m) {
    int row = m * 16 + l15;
    float4 a = *(const float4*)&rs[row][0];
    float4 c = *(const float4*)&rs[row][4];
    float inv = 1.0f / (a.x + a.y + a.z + a.w + c.x + c.y + c.z + c.w);
    float* rp = &attn[attn_base + (size_t)row * 1024 + wave * 128 + l4 * 4];
#pragma unroll
    for (int g = 0; g < 8; ++g) {
      uint2 u = est[m][g];
      f32x4 p = {bf2f((unsigned short)(u.x & 0xFFFF)) * inv,
                 bf2f((unsigned short)(u.x >> 16)) * inv,
                 bf2f((unsigned short)(u.y & 0xFFFF)) * inv,
                 bf2f((unsigned short)(u.y >> 16)) * inv};
      __builtin_nontemporal_store(p, (f32x4*)(rp + g * 16));
    }
  }

  // ---- PV: wave owns 16x16 tile (wm,wn); unnormalized P, scale at end ----
  const int wm = wave >> 2, wn = wave & 3;
  float pinv[4];
#pragma unroll
  for (int i = 0; i < 4; ++i) {
    int row = wm * 16 + l4 * 4 + i;
    float4 a = *(const float4*)&rs[row][0];
    float4 c = *(const float4*)&rs[row][4];
    pinv[i] = 1.0f / (a.x + a.y + a.z + a.w + c.x + c.y + c.z + c.w);
  }
  const unsigned short* vb = vst + ((size_t)b * 64 + wn * 16 + l15) * 1024;
  const unsigned short* pr = &SP[wm * 16 + l15][0];
  f32x4 o0 = {}, o1 = {};
  __builtin_amdgcn_s_setprio(1);
#pragma unroll 8
  for (int jt = 0; jt < 32; jt += 2) {
    bf16x8 pa0 = *(const bf16x8*)&pr[jt * 32 + l4 * 8];
    bf16x8 bv0 = *(const bf16x8*)&vb[jt * 32 + l4 * 8];
    o0 = __builtin_amdgcn_mfma_f32_16x16x32_bf16(pa0, bv0, o0, 0, 0, 0);
    bf16x8 pa1 = *(const bf16x8*)&pr[(jt + 1) * 32 + l4 * 8];
    bf16x8 bv1 = *(const bf16x8*)&vb[(jt + 1) * 32 + l4 * 8];
    o1 = __builtin_amdgcn_mfma_f32_16x16x32_bf16(pa1, bv1, o1, 0, 0, 0);
  }
  __builtin_amdgcn_s_setprio(0);
  float* hb = head + (((size_t)(h * 8 + b) * 1024) + qt * 32 + wm * 16) * 64 + wn * 16;
#pragma unroll
  for (int i = 0; i < 4; ++i)
    hb[(size_t)(l4 * 4 + i) * 64 + l15] = (o0[i] + o1[i]) * pinv[i];
}

// ---------------- 5. fused head-mean + out = pooled @ Wo ----------------
__global__ __launch_bounds__(256) void k_final(const float* __restrict__ head,
                                               const float* __restrict__ Wo,
                                               float* __restrict__ out) {
  __shared__ float Ps[32][68];
  __shared__ float Ws[64][132];
  const int rt = blockIdx.x;
  const int r0 = rt * 32;
  const int t = threadIdx.x;
#pragma unroll
  for (int j = 0; j < 2; ++j) {
    int e = t + j * 256;                  // 512 float4 slots = 32 rows x 16
    int r = e >> 4, k4 = (e & 15) * 4;
    float4 acc = {0.f, 0.f, 0.f, 0.f};
#pragma unroll
    for (int hh = 0; hh < 16; ++hh) {
      float4 v = *(const float4*)&head[((size_t)hh * 8192 + r0 + r) * 64 + k4];
      acc.x += v.x; acc.y += v.y; acc.z += v.z; acc.w += v.w;
    }
    const float s = 1.0f / 16.0f;
    Ps[r][k4] = acc.x * s; Ps[r][k4 + 1] = acc.y * s;
    Ps[r][k4 + 2] = acc.z * s; Ps[r][k4 + 3] = acc.w * s;
  }
  const int ty = t >> 4, tx = t & 15;
  for (int dt = 0; dt < 8; ++dt) {
    int d0 = dt * 128;
#pragma unroll
    for (int j = 0; j < 8; ++j) {
      int e = t + j * 256;
      int k = e >> 5, c4 = (e & 31) * 4;
      *(float4*)&Ws[k][c4] = *(const float4*)&Wo[(size_t)k * 1024 + d0 + c4];
    }
    __syncthreads();
    float acc[2][8] = {};
    for (int k = 0; k < 64; ++k) {
      float a0 = Ps[ty * 2][k], a1 = Ps[ty * 2 + 1][k];
      float4 b0 = *(const float4*)&Ws[k][tx * 8];
      float4 b1 = *(const float4*)&Ws[k][tx * 8 + 4];
      acc[0][0] += a0 * b0.x; acc[0][1] += a0 * b0.y; acc[0][2] += a0 * b0.z; acc[0][3] += a0 * b0.w;
      acc[0][4] += a0 * b1.x; acc[0][5] += a0 * b1.y; acc[0][6] += a0 * b1.z; acc[0][7] += a0 * b1.w;
      acc[1][0] += a1 * b0.x; acc[1][1] += a1 * b0.y; acc[1][2] += a1 * b0.z; acc[1][3] += a1 * b0.w;
      acc[1][4] += a1 * b1.x; acc[1][5] += a1 * b1.y; acc[1][6] += a1 * b1.z; acc[1][7] += a1 * b1.w;
    }
#pragma unroll
    for (int i = 0; i < 2; ++i) {
      float4 v0 = {acc[i][0], acc[i][1], acc[i][2], acc[i][3]};
      float4 v1 = {acc[i][4], acc[i][5], acc[i][6], acc[i][7]};
      size_t o = (size_t)(r0 + ty * 2 + i) * 1024 + d0 + tx * 8;
      *(float4*)&out[o]     = v0;
      *(float4*)&out[o + 4] = v1;
    }
    __syncthreads();
  }
}

extern "C" void kernel_launch(void* const* d_in, const int* in_sizes, int n_in,
                              void* d_out, int out_size, void* d_ws, size_t ws_size,
                              hipStream_t stream) {
  const float* q  = (const float*)d_in[0];
  // d_in[1] (k), d_in[2] (v) are unused by the reference
  const float* Wq = (const float*)d_in[3];
  const float* Wk = (const float*)d_in[4];
  const float* Wv = (const float*)d_in[5];
  const float* Wo = (const float*)d_in[6];

  char* ws = (char*)d_ws;
  unsigned short* qbf   = (unsigned short*)(ws + 0);          // 16,777,216 B
  unsigned short* wcatT = (unsigned short*)(ws + 16777216);   //  4,325,376 B
  unsigned short* Gq    = (unsigned short*)(ws + 21102592);   // 16,777,216 B
  unsigned short* kst   = (unsigned short*)(ws + 37879808);   // 16,777,216 B
  unsigned short* vst   = (unsigned short*)(ws + 54657024);   //  1,048,576 B
  float*          head  = (float*)(ws + 55705600);            // 33,554,432 B

  float* out  = (float*)d_out;
  float* attn = out + (size_t)8 * 1024 * 1024;

  hipLaunchKernelGGL(k_convert_q,   dim3(8192), dim3(256), 0, stream, q, qbf);
  hipLaunchKernelGGL(k_build_wcatT, dim3(1056), dim3(256), 0, stream, Wq, Wk, Wv, wcatT);
  hipLaunchKernelGGL(k_gemm,        dim3(1088), dim3(256), 0, stream, qbf, wcatT, Gq, kst, vst);
  hipLaunchKernelGGL(k_attn,        dim3(4096), dim3(512), 0, stream, Gq, kst, vst, attn, head);
  hipLaunchKernelGGL(k_final,       dim3(256),  dim3(256), 0, stream, head, Wo, out);
}

// Round 19
// 346.597 us; speedup vs baseline: 1.0315x; 1.0315x over previous
//
#include <hip/hip_runtime.h>
#include <hip/hip_bf16.h>
#include <stdint.h>

#define NC 2112   // H*DK*2 + DK = 16*64*2 + 64

typedef __attribute__((ext_vector_type(8))) short bf16x8;
typedef __attribute__((ext_vector_type(4))) float f32x4;

static __device__ __forceinline__ unsigned short f2bf(float f) {
  uint32_t u = __builtin_bit_cast(uint32_t, f);
  u += 0x7FFFu + ((u >> 16) & 1u);
  return (unsigned short)(u >> 16);
}
// native path: compiler emits v_cvt_pk_bf16_f32 (RNE, same bits as f2bf)
static __device__ __forceinline__ unsigned short f2bf_n(float f) {
  __hip_bfloat16 h = __float2bfloat16(f);
  return __builtin_bit_cast(unsigned short, h);
}
static __device__ __forceinline__ float bf2f(unsigned short u) {
  return __builtin_bit_cast(float, ((uint32_t)u) << 16);
}
static __device__ __forceinline__ float exp2_fast(float x) {
  return __builtin_amdgcn_exp2f(x);   // single v_exp_f32 (2^x on gfx950)
}
static __device__ __forceinline__ void gload16(const unsigned short* g, unsigned short* l) {
  __builtin_amdgcn_global_load_lds((const __attribute__((address_space(1))) void*)g,
                                   (__attribute__((address_space(3))) void*)l, 16, 0, 0);
}

// ---------------- 1. q fp32 -> bf16 ----------------
__global__ void k_convert_q(const float* __restrict__ q, unsigned short* __restrict__ qbf) {
  int i = blockIdx.x * blockDim.x + threadIdx.x;   // one float4 each; 2,097,152 total
  float4 v = ((const float4*)q)[i];
  ushort4 o;
  o.x = f2bf(v.x); o.y = f2bf(v.y); o.z = f2bf(v.z); o.w = f2bf(v.w);
  ((ushort4*)qbf)[i] = o;
}

// ---------------- 2. build WcatT[2112][1024] bf16 (N-major, k contiguous) ----------------
// Wq columns pre-scaled by 0.125*log2(e) so attn can use exp2 directly.
__global__ void k_build_wcatT(const float* __restrict__ Wq, const float* __restrict__ Wk,
                              const float* __restrict__ Wv, unsigned short* __restrict__ wt) {
  int t = blockIdx.x * blockDim.x + threadIdx.x;   // c*128 + k/8 ; 270,336 total
  int c = t >> 7;
  int k0 = (t & 127) << 3;
  const float qs = 0.18033688011116027f;  // 0.125 * log2(e)
  unsigned short o[8];
#pragma unroll
  for (int i = 0; i < 8; ++i) {
    int k = k0 + i;
    float v;
    if (c < 1024)      v = Wq[((size_t)(c >> 6) * 1024 + k) * 64 + (c & 63)] * qs;
    else if (c < 2048) v = Wk[((size_t)((c - 1024) >> 6) * 1024 + k) * 64 + (c & 63)];
    else               v = Wv[(size_t)k * 64 + (c - 2048)];
    o[i] = f2bf(v);
  }
  *(ushort4*)&wt[(size_t)c * 1024 + k0]     = *(ushort4*)&o[0];
  *(ushort4*)&wt[(size_t)c * 1024 + k0 + 4] = *(ushort4*)&o[4];
}

// ---------------- 3. GEMM, BK=64 (half the barriers); epilogue splits Q->Gq, K->kst, V->vst ----------------
__global__ __launch_bounds__(256) void k_gemm(const unsigned short* __restrict__ A,
                                              const unsigned short* __restrict__ Bt,
                                              unsigned short* __restrict__ Gq,
                                              unsigned short* __restrict__ kst,
                                              unsigned short* __restrict__ vst) {
  __shared__ unsigned short As[128 * 64];   // linear: required by global_load_lds (16 KB)
  __shared__ unsigned short Bs[128 * 64];
  const int L = blockIdx.x;                 // 1088 = 8 XCD * 136
  const int xcd = L & 7, l = L >> 3;
  const int tn = l >> 3;
  const int tm = xcd * 8 + (l & 7);
  const int rowBase = tm * 128, colBase = tn * 128;
  const int t = threadIdx.x;
  const int wave = t >> 6, lane = t & 63;
  const int wm = wave >> 1, wn = wave & 1;
  const int l15 = lane & 15, l4 = lane >> 4;
  f32x4 acc[4][4] = {};
  for (int kt = 0; kt < 1024; kt += 64) {
#pragma unroll
    for (int i = 0; i < 4; ++i) {
      int e = (t + i * 256) * 8;          // elem index in 128x64 tile
      int r = e >> 6, c = e & 63;
      gload16(&A[(size_t)(rowBase + r) * 1024 + kt + c], &As[e]);
      int rb = colBase + r; rb = rb < NC ? rb : (NC - 1);   // clamp (dup row, never stored)
      gload16(&Bt[(size_t)rb * 1024 + kt + c], &Bs[e]);
    }
    __syncthreads();
#pragma unroll
    for (int ks = 0; ks < 2; ++ks) {
      bf16x8 af[4], bfr[4];
#pragma unroll
      for (int m = 0; m < 4; ++m)
        af[m] = *(const bf16x8*)&As[(wm * 64 + m * 16 + l15) * 64 + ks * 32 + l4 * 8];
#pragma unroll
      for (int n = 0; n < 4; ++n)
        bfr[n] = *(const bf16x8*)&Bs[(wn * 64 + n * 16 + l15) * 64 + ks * 32 + l4 * 8];
#pragma unroll
      for (int m = 0; m < 4; ++m)
#pragma unroll
        for (int n = 0; n < 4; ++n)
          acc[m][n] = __builtin_amdgcn_mfma_f32_16x16x32_bf16(af[m], bfr[n], acc[m][n], 0, 0, 0);
    }
    __syncthreads();
  }
#pragma unroll
  for (int m = 0; m < 4; ++m)
#pragma unroll
    for (int n = 0; n < 4; ++n) {
      int col = colBase + wn * 64 + n * 16 + l15;
      int row0 = rowBase + wm * 64 + m * 16 + l4 * 4;
      if (col < 1024) {
        // Q projections
#pragma unroll
        for (int i = 0; i < 4; ++i)
          Gq[(size_t)(row0 + i) * 1024 + col] = f2bf_n(acc[m][n][i]);
      } else if (col < 2048) {
        // K projections -> dense per-(b,h) panel
        int hh = (col - 1024) >> 6, dk = (col - 1024) & 63;
#pragma unroll
        for (int i = 0; i < 4; ++i) {
          int rg = row0 + i;
          kst[(((size_t)(rg >> 10) * 16 + hh) * 1024 + (rg & 1023)) * 64 + dk] = f2bf_n(acc[m][n][i]);
        }
      } else if (col < NC) {
        // V columns: write transposed into vst[b][d][j]
        int d = col - 2048;
#pragma unroll
        for (int i = 0; i < 4; ++i) {
          int rg = row0 + i;
          vst[((size_t)(rg >> 10) * 64 + d) * 1024 + (rg & 1023)] = f2bf_n(acc[m][n][i]);
        }
      }
    }
}

// ---------------- 4. attention: r17 champion (dense K panels, full-line NT, exp2) ----------------
__global__ __launch_bounds__(512, 4) void k_attn(const unsigned short* __restrict__ Gq,
                                                 const unsigned short* __restrict__ kst,
                                                 const unsigned short* __restrict__ vst,
                                                 float* __restrict__ attn,
                                                 float* __restrict__ head) {
  __shared__ unsigned short SP[32][1032];  // unnormalized exp(scores), bf16
  __shared__ float rs[32][8];              // per-row partial sums, per wave
  const int L = blockIdx.x;                // XCD swizzle: 4096 = 8 * 512
  const int wi = (L & 7) * 512 + (L >> 3);
  const int qt = wi & 31, b = (wi >> 5) & 7, h = wi >> 8;
  const int t = threadIdx.x, wave = t >> 6, lane = t & 63;
  const int l15 = lane & 15, l4 = lane >> 4;

  const unsigned short* Gqb = Gq + (size_t)b * 1024 * 1024;
  const unsigned short* Kb  = kst + (size_t)(b * 16 + h) * 1024 * 64;

  // Q fragments (B-operand): qf[m] covers q-rows qt*32 + m*16 + l15
  bf16x8 qf[2][2];
#pragma unroll
  for (int m = 0; m < 2; ++m)
#pragma unroll
    for (int ks = 0; ks < 2; ++ks)
      qf[m][ks] = *(const bf16x8*)&Gqb[(size_t)(qt * 32 + m * 16 + l15) * 1024 + h * 64 + ks * 32 + l4 * 8];

  // ---- phase 1: QK^T swapped (wave owns keys [wave*128,+128)) ----
  float psum[2] = {};   // row m*16+l15, this lane's share of 128 keys
#pragma unroll
  for (int half = 0; half < 2; ++half) {
    bf16x8 kf[4][2];
#pragma unroll
    for (int kt = 0; kt < 4; ++kt) {
      int k0 = wave * 128 + half * 64 + kt * 16;
#pragma unroll
      for (int ks = 0; ks < 2; ++ks)
        kf[kt][ks] = *(const bf16x8*)&Kb[(size_t)(k0 + l15) * 64 + ks * 32 + l4 * 8];
    }
#pragma unroll
    for (int kt = 0; kt < 4; ++kt) {
      int k0 = wave * 128 + half * 64 + kt * 16;
#pragma unroll
      for (int m = 0; m < 2; ++m) {
        f32x4 s = {};
        __builtin_amdgcn_s_setprio(1);
        s = __builtin_amdgcn_mfma_f32_16x16x32_bf16(kf[kt][0], qf[m][0], s, 0, 0, 0);
        s = __builtin_amdgcn_mfma_f32_16x16x32_bf16(kf[kt][1], qf[m][1], s, 0, 0, 0);
        __builtin_amdgcn_s_setprio(0);
        // lane: q-row = m*16+l15 ; keys = k0 + l4*4 + i
        float e0 = exp2_fast(s[0]), e1 = exp2_fast(s[1]);
        float e2 = exp2_fast(s[2]), e3 = exp2_fast(s[3]);
        psum[m] += (e0 + e1) + (e2 + e3);
        uint32_t lo = (uint32_t)f2bf_n(e0) | ((uint32_t)f2bf_n(e1) << 16);
        uint32_t hi = (uint32_t)f2bf_n(e2) | ((uint32_t)f2bf_n(e3) << 16);
        uint2 u = {lo, hi};
        *(uint2*)&SP[m * 16 + l15][k0 + l4 * 4] = u;
      }
    }
  }
  // reduce over l4 lane bits (lanes 16,32 apart share the same q-row)
  psum[0] += __shfl_xor(psum[0], 16);
  psum[0] += __shfl_xor(psum[0], 32);
  psum[1] += __shfl_xor(psum[1], 16);
  psum[1] += __shfl_xor(psum[1], 32);
  if (l4 == 0) {
    rs[l15][wave]      = psum[0];
    rs[16 + l15][wave] = psum[1];
  }
  __syncthreads();

  // ---- per-row inverse sums ----
  const int wm = wave >> 2, wn = wave & 3;
  float winv[4], pinv[4];
#pragma unroll
  for (int rr = 0; rr < 4; ++rr) {
    int row = wave * 4 + rr;
    float4 a = *(const float4*)&rs[row][0];
    float4 c = *(const float4*)&rs[row][4];
    winv[rr] = 1.0f / (a.x + a.y + a.z + a.w + c.x + c.y + c.z + c.w);
  }
#pragma unroll
  for (int i = 0; i < 4; ++i) {
    int row = wm * 16 + l4 * 4 + i;
    float4 a = *(const float4*)&rs[row][0];
    float4 c = *(const float4*)&rs[row][4];
    pinv[i] = 1.0f / (a.x + a.y + a.z + a.w + c.x + c.y + c.z + c.w);
  }

  // ---- attn write (rows wave*4..+3): full-line NT stores (BEFORE PV) ----
  size_t attn_base = ((size_t)(h * 8 + b) * 1024 + (size_t)qt * 32) * 1024;
#pragma unroll
  for (int rr = 0; rr < 4; ++rr) {
    int row = wave * 4 + rr;
    float inv = winv[rr];
#pragma unroll
    for (int c = 0; c < 4; ++c) {
      uint2 u = *(const uint2*)&SP[row][c * 256 + lane * 4];
      f32x4 p = {bf2f((unsigned short)(u.x & 0xFFFF)) * inv,
                 bf2f((unsigned short)(u.x >> 16)) * inv,
                 bf2f((unsigned short)(u.y & 0xFFFF)) * inv,
                 bf2f((unsigned short)(u.y >> 16)) * inv};
      __builtin_nontemporal_store(p,
          (f32x4*)&attn[attn_base + (size_t)row * 1024 + c * 256 + lane * 4]);
    }
  }

  // ---- PV: wave owns 16x16 tile (wm,wn); unnormalized P, scale at end ----
  const unsigned short* vb = vst + ((size_t)b * 64 + wn * 16 + l15) * 1024;
  const unsigned short* pr = &SP[wm * 16 + l15][0];
  f32x4 o0 = {}, o1 = {};
  __builtin_amdgcn_s_setprio(1);
#pragma unroll 8
  for (int jt = 0; jt < 32; jt += 2) {
    bf16x8 pa0 = *(const bf16x8*)&pr[jt * 32 + l4 * 8];
    bf16x8 bv0 = *(const bf16x8*)&vb[jt * 32 + l4 * 8];
    o0 = __builtin_amdgcn_mfma_f32_16x16x32_bf16(pa0, bv0, o0, 0, 0, 0);
    bf16x8 pa1 = *(const bf16x8*)&pr[(jt + 1) * 32 + l4 * 8];
    bf16x8 bv1 = *(const bf16x8*)&vb[(jt + 1) * 32 + l4 * 8];
    o1 = __builtin_amdgcn_mfma_f32_16x16x32_bf16(pa1, bv1, o1, 0, 0, 0);
  }
  __builtin_amdgcn_s_setprio(0);
  float* hb = head + (((size_t)(h * 8 + b) * 1024) + qt * 32 + wm * 16) * 64 + wn * 16;
#pragma unroll
  for (int i = 0; i < 4; ++i)
    hb[(size_t)(l4 * 4 + i) * 64 + l15] = (o0[i] + o1[i]) * pinv[i];
}

// ---------------- 5. fused head-mean + out = pooled @ Wo ----------------
__global__ __launch_bounds__(256) void k_final(const float* __restrict__ head,
                                               const float* __restrict__ Wo,
                                               float* __restrict__ out) {
  __shared__ float Ps[32][68];
  __shared__ float Ws[64][132];
  const int rt = blockIdx.x;
  const int r0 = rt * 32;
  const int t = threadIdx.x;
#pragma unroll
  for (int j = 0; j < 2; ++j) {
    int e = t + j * 256;                  // 512 float4 slots = 32 rows x 16
    int r = e >> 4, k4 = (e & 15) * 4;
    float4 acc = {0.f, 0.f, 0.f, 0.f};
#pragma unroll
    for (int hh = 0; hh < 16; ++hh) {
      float4 v = *(const float4*)&head[((size_t)hh * 8192 + r0 + r) * 64 + k4];
      acc.x += v.x; acc.y += v.y; acc.z += v.z; acc.w += v.w;
    }
    const float s = 1.0f / 16.0f;
    Ps[r][k4] = acc.x * s; Ps[r][k4 + 1] = acc.y * s;
    Ps[r][k4 + 2] = acc.z * s; Ps[r][k4 + 3] = acc.w * s;
  }
  const int ty = t >> 4, tx = t & 15;
  for (int dt = 0; dt < 8; ++dt) {
    int d0 = dt * 128;
#pragma unroll
    for (int j = 0; j < 8; ++j) {
      int e = t + j * 256;
      int k = e >> 5, c4 = (e & 31) * 4;
      *(float4*)&Ws[k][c4] = *(const float4*)&Wo[(size_t)k * 1024 + d0 + c4];
    }
    __syncthreads();
    float acc[2][8] = {};
    for (int k = 0; k < 64; ++k) {
      float a0 = Ps[ty * 2][k], a1 = Ps[ty * 2 + 1][k];
      float4 b0 = *(const float4*)&Ws[k][tx * 8];
      float4 b1 = *(const float4*)&Ws[k][tx * 8 + 4];
      acc[0][0] += a0 * b0.x; acc[0][1] += a0 * b0.y; acc[0][2] += a0 * b0.z; acc[0][3] += a0 * b0.w;
      acc[0][4] += a0 * b1.x; acc[0][5] += a0 * b1.y; acc[0][6] += a0 * b1.z; acc[0][7] += a0 * b1.w;
      acc[1][0] += a1 * b0.x; acc[1][1] += a1 * b0.y; acc[1][2] += a1 * b0.z; acc[1][3] += a1 * b0.w;
      acc[1][4] += a1 * b1.x; acc[1][5] += a1 * b1.y; acc[1][6] += a1 * b1.z; acc[1][7] += a1 * b1.w;
    }
#pragma unroll
    for (int i = 0; i < 2; ++i) {
      float4 v0 = {acc[i][0], acc[i][1], acc[i][2], acc[i][3]};
      float4 v1 = {acc[i][4], acc[i][5], acc[i][6], acc[i][7]};
      size_t o = (size_t)(r0 + ty * 2 + i) * 1024 + d0 + tx * 8;
      *(float4*)&out[o]     = v0;
      *(float4*)&out[o + 4] = v1;
    }
    __syncthreads();
  }
}

extern "C" void kernel_launch(void* const* d_in, const int* in_sizes, int n_in,
                              void* d_out, int out_size, void* d_ws, size_t ws_size,
                              hipStream_t stream) {
  const float* q  = (const float*)d_in[0];
  // d_in[1] (k), d_in[2] (v) are unused by the reference
  const float* Wq = (const float*)d_in[3];
  const float* Wk = (const float*)d_in[4];
  const float* Wv = (const float*)d_in[5];
  const float* Wo = (const float*)d_in[6];

  char* ws = (char*)d_ws;
  unsigned short* qbf   = (unsigned short*)(ws + 0);          // 16,777,216 B
  unsigned short* wcatT = (unsigned short*)(ws + 16777216);   //  4,325,376 B
  unsigned short* Gq    = (unsigned short*)(ws + 21102592);   // 16,777,216 B
  unsigned short* kst   = (unsigned short*)(ws + 37879808);   // 16,777,216 B
  unsigned short* vst   = (unsigned short*)(ws + 54657024);   //  1,048,576 B
  float*          head  = (float*)(ws + 55705600);            // 33,554,432 B

  float* out  = (float*)d_out;
  float* attn = out + (size_t)8 * 1024 * 1024;

  hipLaunchKernelGGL(k_convert_q,   dim3(8192), dim3(256), 0, stream, q, qbf);
  hipLaunchKernelGGL(k_build_wcatT, dim3(1056), dim3(256), 0, stream, Wq, Wk, Wv, wcatT);
  hipLaunchKernelGGL(k_gemm,        dim3(1088), dim3(256), 0, stream, qbf, wcatT, Gq, kst, vst);
  hipLaunchKernelGGL(k_attn,        dim3(4096), dim3(512), 0, stream, Gq, kst, vst, attn, head);
  hipLaunchKernelGGL(k_final,       dim3(256),  dim3(256), 0, stream, head, Wo, out);
}

// Round 20
// 322.234 us; speedup vs baseline: 1.1095x; 1.0756x over previous
//
#include <hip/hip_runtime.h>
#include <hip/hip_bf16.h>
#include <stdint.h>

#define NC 2112   // H*DK*2 + DK = 16*64*2 + 64

typedef __attribute__((ext_vector_type(8))) short bf16x8;
typedef __attribute__((ext_vector_type(4))) float f32x4;

static __device__ __forceinline__ unsigned short f2bf(float f) {
  uint32_t u = __builtin_bit_cast(uint32_t, f);
  u += 0x7FFFu + ((u >> 16) & 1u);
  return (unsigned short)(u >> 16);
}
// native path: compiler emits v_cvt_pk_bf16_f32 (RNE, same bits as f2bf)
static __device__ __forceinline__ unsigned short f2bf_n(float f) {
  __hip_bfloat16 h = __float2bfloat16(f);
  return __builtin_bit_cast(unsigned short, h);
}
static __device__ __forceinline__ float bf2f(unsigned short u) {
  return __builtin_bit_cast(float, ((uint32_t)u) << 16);
}
static __device__ __forceinline__ float exp2_fast(float x) {
  return __builtin_amdgcn_exp2f(x);   // single v_exp_f32 (2^x on gfx950)
}
static __device__ __forceinline__ void gload16(const unsigned short* g, unsigned short* l) {
  __builtin_amdgcn_global_load_lds((const __attribute__((address_space(1))) void*)g,
                                   (__attribute__((address_space(3))) void*)l, 16, 0, 0);
}

// ---------------- 1. q fp32 -> bf16 ----------------
__global__ void k_convert_q(const float* __restrict__ q, unsigned short* __restrict__ qbf) {
  int i = blockIdx.x * blockDim.x + threadIdx.x;   // one float4 each; 2,097,152 total
  float4 v = ((const float4*)q)[i];
  ushort4 o;
  o.x = f2bf(v.x); o.y = f2bf(v.y); o.z = f2bf(v.z); o.w = f2bf(v.w);
  ((ushort4*)qbf)[i] = o;
}

// ---------------- 2. build WcatT[2112][1024] bf16 (N-major, k contiguous) ----------------
// Wq columns pre-scaled by 0.125*log2(e) so attn can use exp2 directly.
__global__ void k_build_wcatT(const float* __restrict__ Wq, const float* __restrict__ Wk,
                              const float* __restrict__ Wv, unsigned short* __restrict__ wt) {
  int t = blockIdx.x * blockDim.x + threadIdx.x;   // c*128 + k/8 ; 270,336 total
  int c = t >> 7;
  int k0 = (t & 127) << 3;
  const float qs = 0.18033688011116027f;  // 0.125 * log2(e)
  unsigned short o[8];
#pragma unroll
  for (int i = 0; i < 8; ++i) {
    int k = k0 + i;
    float v;
    if (c < 1024)      v = Wq[((size_t)(c >> 6) * 1024 + k) * 64 + (c & 63)] * qs;
    else if (c < 2048) v = Wk[((size_t)((c - 1024) >> 6) * 1024 + k) * 64 + (c & 63)];
    else               v = Wv[(size_t)k * 64 + (c - 2048)];
    o[i] = f2bf(v);
  }
  *(ushort4*)&wt[(size_t)c * 1024 + k0]     = *(ushort4*)&o[0];
  *(ushort4*)&wt[(size_t)c * 1024 + k0 + 4] = *(ushort4*)&o[4];
}

// ---------------- 3. GEMM (m97 pattern, BK=32); epilogue splits Q->Gq, K->kst panels, V->vst ----------------
__global__ __launch_bounds__(256) void k_gemm(const unsigned short* __restrict__ A,
                                              const unsigned short* __restrict__ Bt,
                                              unsigned short* __restrict__ Gq,
                                              unsigned short* __restrict__ kst,
                                              unsigned short* __restrict__ vst) {
  __shared__ unsigned short As[128 * 32];   // linear: required by global_load_lds
  __shared__ unsigned short Bs[128 * 32];
  const int L = blockIdx.x;                 // 1088 = 8 XCD * 136
  const int xcd = L & 7, l = L >> 3;
  const int tn = l >> 3;
  const int tm = xcd * 8 + (l & 7);
  const int rowBase = tm * 128, colBase = tn * 128;
  const int t = threadIdx.x;
  const int wave = t >> 6, lane = t & 63;
  const int wm = wave >> 1, wn = wave & 1;
  const int l15 = lane & 15, l4 = lane >> 4;
  f32x4 acc[4][4] = {};
  for (int kt = 0; kt < 1024; kt += 32) {
#pragma unroll
    for (int i = 0; i < 2; ++i) {
      int e = (t + i * 256) * 8;          // elem index in 128x32 tile
      int r = e >> 5, c = e & 31;
      gload16(&A[(size_t)(rowBase + r) * 1024 + kt + c], &As[e]);
      int rb = colBase + r; rb = rb < NC ? rb : (NC - 1);   // clamp (dup row, never stored)
      gload16(&Bt[(size_t)rb * 1024 + kt + c], &Bs[e]);
    }
    __syncthreads();
    bf16x8 af[4], bfr[4];
#pragma unroll
    for (int m = 0; m < 4; ++m) af[m] = *(const bf16x8*)&As[(wm * 64 + m * 16 + l15) * 32 + l4 * 8];
#pragma unroll
    for (int n = 0; n < 4; ++n) bfr[n] = *(const bf16x8*)&Bs[(wn * 64 + n * 16 + l15) * 32 + l4 * 8];
#pragma unroll
    for (int m = 0; m < 4; ++m)
#pragma unroll
      for (int n = 0; n < 4; ++n)
        acc[m][n] = __builtin_amdgcn_mfma_f32_16x16x32_bf16(af[m], bfr[n], acc[m][n], 0, 0, 0);
    __syncthreads();
  }
#pragma unroll
  for (int m = 0; m < 4; ++m)
#pragma unroll
    for (int n = 0; n < 4; ++n) {
      int col = colBase + wn * 64 + n * 16 + l15;
      int row0 = rowBase + wm * 64 + m * 16 + l4 * 4;
      if (col < 1024) {
        // Q projections
#pragma unroll
        for (int i = 0; i < 4; ++i)
          Gq[(size_t)(row0 + i) * 1024 + col] = f2bf_n(acc[m][n][i]);
      } else if (col < 2048) {
        // K projections -> dense per-(b,h) panel
        int hh = (col - 1024) >> 6, dk = (col - 1024) & 63;
#pragma unroll
        for (int i = 0; i < 4; ++i) {
          int rg = row0 + i;
          kst[(((size_t)(rg >> 10) * 16 + hh) * 1024 + (rg & 1023)) * 64 + dk] = f2bf_n(acc[m][n][i]);
        }
      } else if (col < NC) {
        // V columns: write transposed into vst[b][d][j]
        int d = col - 2048;
#pragma unroll
        for (int i = 0; i < 4; ++i) {
          int rg = row0 + i;
          vst[((size_t)(rg >> 10) * 64 + d) * 1024 + (rg & 1023)] = f2bf_n(acc[m][n][i]);
        }
      }
    }
}

// ---------------- 4. attention: champion (dense K panels, swapped QK^T, full-line NT, exp2) ----------------
__global__ __launch_bounds__(512, 4) void k_attn(const unsigned short* __restrict__ Gq,
                                                 const unsigned short* __restrict__ kst,
                                                 const unsigned short* __restrict__ vst,
                                                 float* __restrict__ attn,
                                                 float* __restrict__ head) {
  __shared__ unsigned short SP[32][1032];  // unnormalized exp(scores), bf16
  __shared__ float rs[32][8];              // per-row partial sums, per wave
  const int L = blockIdx.x;                // XCD swizzle: 4096 = 8 * 512
  const int wi = (L & 7) * 512 + (L >> 3);
  const int qt = wi & 31, b = (wi >> 5) & 7, h = wi >> 8;
  const int t = threadIdx.x, wave = t >> 6, lane = t & 63;
  const int l15 = lane & 15, l4 = lane >> 4;

  const unsigned short* Gqb = Gq + (size_t)b * 1024 * 1024;
  const unsigned short* Kb  = kst + (size_t)(b * 16 + h) * 1024 * 64;

  // Q fragments (B-operand): qf[m] covers q-rows qt*32 + m*16 + l15
  bf16x8 qf[2][2];
#pragma unroll
  for (int m = 0; m < 2; ++m)
#pragma unroll
    for (int ks = 0; ks < 2; ++ks)
      qf[m][ks] = *(const bf16x8*)&Gqb[(size_t)(qt * 32 + m * 16 + l15) * 1024 + h * 64 + ks * 32 + l4 * 8];

  // ---- phase 1: QK^T swapped (wave owns keys [wave*128,+128)) ----
  float psum[2] = {};   // row m*16+l15, this lane's share of 128 keys
#pragma unroll
  for (int half = 0; half < 2; ++half) {
    bf16x8 kf[4][2];
#pragma unroll
    for (int kt = 0; kt < 4; ++kt) {
      int k0 = wave * 128 + half * 64 + kt * 16;
#pragma unroll
      for (int ks = 0; ks < 2; ++ks)
        kf[kt][ks] = *(const bf16x8*)&Kb[(size_t)(k0 + l15) * 64 + ks * 32 + l4 * 8];
    }
#pragma unroll
    for (int kt = 0; kt < 4; ++kt) {
      int k0 = wave * 128 + half * 64 + kt * 16;
#pragma unroll
      for (int m = 0; m < 2; ++m) {
        f32x4 s = {};
        __builtin_amdgcn_s_setprio(1);
        s = __builtin_amdgcn_mfma_f32_16x16x32_bf16(kf[kt][0], qf[m][0], s, 0, 0, 0);
        s = __builtin_amdgcn_mfma_f32_16x16x32_bf16(kf[kt][1], qf[m][1], s, 0, 0, 0);
        __builtin_amdgcn_s_setprio(0);
        // lane: q-row = m*16+l15 ; keys = k0 + l4*4 + i
        float e0 = exp2_fast(s[0]), e1 = exp2_fast(s[1]);
        float e2 = exp2_fast(s[2]), e3 = exp2_fast(s[3]);
        psum[m] += (e0 + e1) + (e2 + e3);
        uint32_t lo = (uint32_t)f2bf_n(e0) | ((uint32_t)f2bf_n(e1) << 16);
        uint32_t hi = (uint32_t)f2bf_n(e2) | ((uint32_t)f2bf_n(e3) << 16);
        uint2 u = {lo, hi};
        *(uint2*)&SP[m * 16 + l15][k0 + l4 * 4] = u;
      }
    }
  }
  // reduce over l4 lane bits (lanes 16,32 apart share the same q-row)
  psum[0] += __shfl_xor(psum[0], 16);
  psum[0] += __shfl_xor(psum[0], 32);
  psum[1] += __shfl_xor(psum[1], 16);
  psum[1] += __shfl_xor(psum[1], 32);
  if (l4 == 0) {
    rs[l15][wave]      = psum[0];
    rs[16 + l15][wave] = psum[1];
  }
  __syncthreads();

  // ---- per-row inverse sums ----
  const int wm = wave >> 2, wn = wave & 3;
  float winv[4], pinv[4];
#pragma unroll
  for (int rr = 0; rr < 4; ++rr) {
    int row = wave * 4 + rr;
    float4 a = *(const float4*)&rs[row][0];
    float4 c = *(const float4*)&rs[row][4];
    winv[rr] = 1.0f / (a.x + a.y + a.z + a.w + c.x + c.y + c.z + c.w);
  }
#pragma unroll
  for (int i = 0; i < 4; ++i) {
    int row = wm * 16 + l4 * 4 + i;
    float4 a = *(const float4*)&rs[row][0];
    float4 c = *(const float4*)&rs[row][4];
    pinv[i] = 1.0f / (a.x + a.y + a.z + a.w + c.x + c.y + c.z + c.w);
  }

  // ---- attn write (rows wave*4..+3): full-line NT stores (BEFORE PV) ----
  size_t attn_base = ((size_t)(h * 8 + b) * 1024 + (size_t)qt * 32) * 1024;
#pragma unroll
  for (int rr = 0; rr < 4; ++rr) {
    int row = wave * 4 + rr;
    float inv = winv[rr];
#pragma unroll
    for (int c = 0; c < 4; ++c) {
      uint2 u = *(const uint2*)&SP[row][c * 256 + lane * 4];
      f32x4 p = {bf2f((unsigned short)(u.x & 0xFFFF)) * inv,
                 bf2f((unsigned short)(u.x >> 16)) * inv,
                 bf2f((unsigned short)(u.y & 0xFFFF)) * inv,
                 bf2f((unsigned short)(u.y >> 16)) * inv};
      __builtin_nontemporal_store(p,
          (f32x4*)&attn[attn_base + (size_t)row * 1024 + c * 256 + lane * 4]);
    }
  }

  // ---- PV: wave owns 16x16 tile (wm,wn); unnormalized P, scale at end ----
  const unsigned short* vb = vst + ((size_t)b * 64 + wn * 16 + l15) * 1024;
  const unsigned short* pr = &SP[wm * 16 + l15][0];
  f32x4 o0 = {}, o1 = {};
  __builtin_amdgcn_s_setprio(1);
#pragma unroll 8
  for (int jt = 0; jt < 32; jt += 2) {
    bf16x8 pa0 = *(const bf16x8*)&pr[jt * 32 + l4 * 8];
    bf16x8 bv0 = *(const bf16x8*)&vb[jt * 32 + l4 * 8];
    o0 = __builtin_amdgcn_mfma_f32_16x16x32_bf16(pa0, bv0, o0, 0, 0, 0);
    bf16x8 pa1 = *(const bf16x8*)&pr[(jt + 1) * 32 + l4 * 8];
    bf16x8 bv1 = *(const bf16x8*)&vb[(jt + 1) * 32 + l4 * 8];
    o1 = __builtin_amdgcn_mfma_f32_16x16x32_bf16(pa1, bv1, o1, 0, 0, 0);
  }
  __builtin_amdgcn_s_setprio(0);
  float* hb = head + (((size_t)(h * 8 + b) * 1024) + qt * 32 + wm * 16) * 64 + wn * 16;
#pragma unroll
  for (int i = 0; i < 4; ++i)
    hb[(size_t)(l4 * 4 + i) * 64 + l15] = (o0[i] + o1[i]) * pinv[i];
}

// ---------------- 5. fused head-mean + out = pooled @ Wo ----------------
__global__ __launch_bounds__(256) void k_final(const float* __restrict__ head,
                                               const float* __restrict__ Wo,
                                               float* __restrict__ out) {
  __shared__ float Ps[32][68];
  __shared__ float Ws[64][132];
  const int rt = blockIdx.x;
  const int r0 = rt * 32;
  const int t = threadIdx.x;
#pragma unroll
  for (int j = 0; j < 2; ++j) {
    int e = t + j * 256;                  // 512 float4 slots = 32 rows x 16
    int r = e >> 4, k4 = (e & 15) * 4;
    float4 acc = {0.f, 0.f, 0.f, 0.f};
#pragma unroll
    for (int hh = 0; hh < 16; ++hh) {
      float4 v = *(const float4*)&head[((size_t)hh * 8192 + r0 + r) * 64 + k4];
      acc.x += v.x; acc.y += v.y; acc.z += v.z; acc.w += v.w;
    }
    const float s = 1.0f / 16.0f;
    Ps[r][k4] = acc.x * s; Ps[r][k4 + 1] = acc.y * s;
    Ps[r][k4 + 2] = acc.z * s; Ps[r][k4 + 3] = acc.w * s;
  }
  const int ty = t >> 4, tx = t & 15;
  for (int dt = 0; dt < 8; ++dt) {
    int d0 = dt * 128;
#pragma unroll
    for (int j = 0; j < 8; ++j) {
      int e = t + j * 256;
      int k = e >> 5, c4 = (e & 31) * 4;
      *(float4*)&Ws[k][c4] = *(const float4*)&Wo[(size_t)k * 1024 + d0 + c4];
    }
    __syncthreads();
    float acc[2][8] = {};
    for (int k = 0; k < 64; ++k) {
      float a0 = Ps[ty * 2][k], a1 = Ps[ty * 2 + 1][k];
      float4 b0 = *(const float4*)&Ws[k][tx * 8];
      float4 b1 = *(const float4*)&Ws[k][tx * 8 + 4];
      acc[0][0] += a0 * b0.x; acc[0][1] += a0 * b0.y; acc[0][2] += a0 * b0.z; acc[0][3] += a0 * b0.w;
      acc[0][4] += a0 * b1.x; acc[0][5] += a0 * b1.y; acc[0][6] += a0 * b1.z; acc[0][7] += a0 * b1.w;
      acc[1][0] += a1 * b0.x; acc[1][1] += a1 * b0.y; acc[1][2] += a1 * b0.z; acc[1][3] += a1 * b0.w;
      acc[1][4] += a1 * b1.x; acc[1][5] += a1 * b1.y; acc[1][6] += a1 * b1.z; acc[1][7] += a1 * b1.w;
    }
#pragma unroll
    for (int i = 0; i < 2; ++i) {
      float4 v0 = {acc[i][0], acc[i][1], acc[i][2], acc[i][3]};
      float4 v1 = {acc[i][4], acc[i][5], acc[i][6], acc[i][7]};
      size_t o = (size_t)(r0 + ty * 2 + i) * 1024 + d0 + tx * 8;
      *(float4*)&out[o]     = v0;
      *(float4*)&out[o + 4] = v1;
    }
    __syncthreads();
  }
}

extern "C" void kernel_launch(void* const* d_in, const int* in_sizes, int n_in,
                              void* d_out, int out_size, void* d_ws, size_t ws_size,
                              hipStream_t stream) {
  const float* q  = (const float*)d_in[0];
  // d_in[1] (k), d_in[2] (v) are unused by the reference
  const float* Wq = (const float*)d_in[3];
  const float* Wk = (const float*)d_in[4];
  const float* Wv = (const float*)d_in[5];
  const float* Wo = (const float*)d_in[6];

  char* ws = (char*)d_ws;
  unsigned short* qbf   = (unsigned short*)(ws + 0);          // 16,777,216 B
  unsigned short* wcatT = (unsigned short*)(ws + 16777216);   //  4,325,376 B
  unsigned short* Gq    = (unsigned short*)(ws + 21102592);   // 16,777,216 B
  unsigned short* kst   = (unsigned short*)(ws + 37879808);   // 16,777,216 B
  unsigned short* vst   = (unsigned short*)(ws + 54657024);   //  1,048,576 B
  float*          head  = (float*)(ws + 55705600);            // 33,554,432 B

  float* out  = (float*)d_out;
  float* attn = out + (size_t)8 * 1024 * 1024;

  hipLaunchKernelGGL(k_convert_q,   dim3(8192), dim3(256), 0, stream, q, qbf);
  hipLaunchKernelGGL(k_build_wcatT, dim3(1056), dim3(256), 0, stream, Wq, Wk, Wv, wcatT);
  hipLaunchKernelGGL(k_gemm,        dim3(1088), dim3(256), 0, stream, qbf, wcatT, Gq, kst, vst);
  hipLaunchKernelGGL(k_attn,        dim3(4096), dim3(512), 0, stream, Gq, kst, vst, attn, head);
  hipLaunchKernelGGL(k_final,       dim3(256),  dim3(256), 0, stream, head, Wo, out);
}